// Round 1
// baseline (1025.728 us; speedup 1.0000x reference)
//
#include <hip/hip_runtime.h>
#include <hip/hip_bf16.h>

#define B_    16
#define CIN_  512
#define COUT_ 512
#define K_    3
#define T_    2048
#define S_    128

#define LIN_SCALE  0.08838834764831845f   // 1/sqrt(128)
#define CONV_SCALE 0.014731391274719739f  // 1/sqrt(512*9)

// ---------------- K1: style projection  s[b,i] = lin_scale * <c_trg[b], style_w[i]> + style_b[i]
__global__ void k_style(const float* __restrict__ c_trg,
                        const float* __restrict__ style_w,
                        const float* __restrict__ style_b,
                        float* __restrict__ s_out) {
    int idx = blockIdx.x * 256 + threadIdx.x;       // 0..8191
    int b = idx >> 9, i = idx & 511;
    const float4* c4 = reinterpret_cast<const float4*>(c_trg + b * S_);
    const float4* w4 = reinterpret_cast<const float4*>(style_w + (size_t)i * S_);
    float acc = 0.f;
#pragma unroll
    for (int j = 0; j < S_ / 4; ++j) {
        float4 a = c4[j], w = w4[j];
        acc += a.x * w.x + a.y * w.y + a.z * w.z + a.w * w.w;
    }
    s_out[idx] = acc * LIN_SCALE + style_b[i];
}

// ---------------- K2: per-(b,o) stats.  alpha = demod*conv_scale, beta = demod*mean
// demod uses UNcentered sum of squares of w = conv_scale*s_i*(cw+1).
__global__ void k_stats(const float* __restrict__ s,
                        const float* __restrict__ conv_w,
                        float* __restrict__ alpha, float* __restrict__ beta) {
    int bo = blockIdx.x;            // b*512 + o
    int b = bo >> 9, o = bo & 511;
    const float* sb = s + b * CIN_;
    const float* wr = conv_w + (size_t)o * (CIN_ * K_);
    float sum = 0.f, sq = 0.f;
    for (int r = threadIdx.x; r < CIN_ * K_; r += 256) {
        int i = r / 3;
        float v = CONV_SCALE * sb[i] * (wr[r] + 1.0f);
        sum += v; sq += v * v;
    }
    for (int off = 32; off; off >>= 1) {
        sum += __shfl_down(sum, off);
        sq  += __shfl_down(sq, off);
    }
    __shared__ float red[8];
    int lane = threadIdx.x & 63, wid = threadIdx.x >> 6;
    if (lane == 0) { red[wid] = sum; red[4 + wid] = sq; }
    __syncthreads();
    if (threadIdx.x == 0) {
        float Ssum = red[0] + red[1] + red[2] + red[3];
        float Q    = red[4] + red[5] + red[6] + red[7];
        float mean  = Ssum * (1.0f / (CIN_ * K_));
        float demod = 1.0f / sqrtf(Q + 1e-8f);
        alpha[bo] = demod * CONV_SCALE;
        beta[bo]  = demod * mean;
    }
}

// ---------------- K3: column sums over CIN:  cx[b,t]=sum_i x, cy[b,t]=sum_i s_i*x
__global__ void k_colsum(const float* __restrict__ x,
                         const float* __restrict__ s,
                         float* __restrict__ cx, float* __restrict__ cy) {
    int t  = blockIdx.x * 256 + threadIdx.x;
    int b  = blockIdx.z;
    int i0 = blockIdx.y * 128;
    const float* xb = x + ((size_t)(b * CIN_ + i0)) * T_ + t;
    const float* sb = s + b * CIN_ + i0;
    float ax = 0.f, ay = 0.f;
    for (int i = 0; i < 128; ++i) {
        float xv = xb[(size_t)i * T_];
        ax += xv;
        ay += sb[i] * xv;
    }
    atomicAdd(&cx[b * T_ + t], ax);
    atomicAdd(&cy[b * T_ + t], ay);
}

// ---------------- K4: transpose conv_w [o][r] -> cwT [r][o]  (r = i*3+k), for coalesced staging
__global__ void k_wt(const float* __restrict__ conv_w, float* __restrict__ cwT) {
    int idx = blockIdx.x * 256 + threadIdx.x;   // < 786432
    int r = idx >> 9, o = idx & 511;
    cwT[idx] = conv_w[(size_t)o * (CIN_ * K_) + r];
}

// ---------------- K5: conv-as-GEMM, fp32 vector.  64(o) x 64(t) tile / block, 256 threads.
// G[o,t] = sum_{i,k} cw[o,i,k] * y_pad[b,i,t+k-1];  out = alpha*(G+cy3) - beta*cx3
__global__ __launch_bounds__(256) void k_conv(
    const float* __restrict__ x, const float* __restrict__ s,
    const float* __restrict__ cwT,
    const float* __restrict__ alpha, const float* __restrict__ beta,
    const float* __restrict__ cx, const float* __restrict__ cy,
    float* __restrict__ out) {

    __shared__ float As[4][192];   // [ii][o_local*3 + k]
    __shared__ float Xs[4][72];    // [ii][m], m = 0..65 -> y_pad[t0-1+m]

    int tid = threadIdx.x;
    int tx = tid & 15, ty = tid >> 4;
    int t0 = blockIdx.x * 64;
    int o0 = blockIdx.y * 64;
    int b  = blockIdx.z;
    int ii = tid >> 6, lane = tid & 63;

    const float* sb = s + b * CIN_;
    float acc[4][4] = {};

    for (int i0 = 0; i0 < CIN_; i0 += 4) {
        // global loads (registers only; overlaps previous compute)
        const float* aT = cwT + (size_t)(i0 + ii) * 3 * COUT_ + o0 + lane;
        float a0 = aT[0], a1 = aT[COUT_], a2 = aT[2 * COUT_];

        const float* xrow = x + ((size_t)(b * CIN_ + i0 + ii)) * T_;
        float sv = sb[i0 + ii];
        int g = t0 - 1 + lane;
        float xv = (g >= 0 && g < T_) ? xrow[g] : 0.f;
        float xv2 = 0.f;
        if (lane < 2) {
            int g2 = t0 + 63 + lane;
            xv2 = (g2 < T_) ? xrow[g2] : 0.f;
        }

        __syncthreads();   // previous iteration done reading LDS
        As[ii][lane * 3 + 0] = a0;
        As[ii][lane * 3 + 1] = a1;
        As[ii][lane * 3 + 2] = a2;
        Xs[ii][lane] = sv * xv;
        if (lane < 2) Xs[ii][64 + lane] = sv * xv2;
        __syncthreads();

#pragma unroll
        for (int u = 0; u < 4; ++u) {
            float4 xa  = *reinterpret_cast<const float4*>(&Xs[u][tx * 4]);
            float2 xb2 = *reinterpret_cast<const float2*>(&Xs[u][tx * 4 + 4]);
            float xsv[6] = {xa.x, xa.y, xa.z, xa.w, xb2.x, xb2.y};
            float4 w0 = *reinterpret_cast<const float4*>(&As[u][ty * 12]);
            float4 w1 = *reinterpret_cast<const float4*>(&As[u][ty * 12 + 4]);
            float4 w2 = *reinterpret_cast<const float4*>(&As[u][ty * 12 + 8]);
            float wf[12] = {w0.x, w0.y, w0.z, w0.w, w1.x, w1.y, w1.z, w1.w,
                            w2.x, w2.y, w2.z, w2.w};
#pragma unroll
            for (int jo = 0; jo < 4; ++jo)
#pragma unroll
                for (int jt = 0; jt < 4; ++jt)
                    acc[jo][jt] += wf[jo * 3 + 0] * xsv[jt]
                                 + wf[jo * 3 + 1] * xsv[jt + 1]
                                 + wf[jo * 3 + 2] * xsv[jt + 2];
        }
    }

    // epilogue: out = alpha*(G + cy3) - beta*cx3
    const float* ab  = alpha + b * COUT_ + o0;
    const float* bb  = beta  + b * COUT_ + o0;
    const float* cxb = cx + b * T_;
    const float* cyb = cy + b * T_;
    float* ob = out + ((size_t)(b * COUT_ + o0)) * T_;
#pragma unroll
    for (int jt = 0; jt < 4; ++jt) {
        int tt = t0 + tx * 4 + jt;
        float cx3 = cxb[tt] + (tt > 0 ? cxb[tt - 1] : 0.f) + (tt < T_ - 1 ? cxb[tt + 1] : 0.f);
        float cy3 = cyb[tt] + (tt > 0 ? cyb[tt - 1] : 0.f) + (tt < T_ - 1 ? cyb[tt + 1] : 0.f);
#pragma unroll
        for (int jo = 0; jo < 4; ++jo) {
            int ol = ty * 4 + jo;
            ob[(size_t)ol * T_ + tt] = ab[ol] * (acc[jo][jt] + cy3) - bb[ol] * cx3;
        }
    }
}

extern "C" void kernel_launch(void* const* d_in, const int* in_sizes, int n_in,
                              void* d_out, int out_size, void* d_ws, size_t ws_size,
                              hipStream_t stream) {
    const float* x       = (const float*)d_in[0];
    const float* c_trg   = (const float*)d_in[1];
    const float* style_w = (const float*)d_in[2];
    const float* style_b = (const float*)d_in[3];
    const float* conv_w  = (const float*)d_in[4];
    float* out = (float*)d_out;
    float* ws  = (float*)d_ws;

    float* s_buf = ws;             // 8192
    float* alpha = ws + 8192;      // 8192
    float* beta  = ws + 16384;     // 8192
    float* cx    = ws + 24576;     // 32768
    float* cy    = ws + 57344;     // 32768
    float* cwT   = ws + 90112;     // 786432

    hipMemsetAsync(cx, 0, (size_t)2 * B_ * T_ * sizeof(float), stream);

    k_style<<<dim3((B_ * CIN_) / 256), 256, 0, stream>>>(c_trg, style_w, style_b, s_buf);
    k_stats<<<dim3(B_ * COUT_), 256, 0, stream>>>(s_buf, conv_w, alpha, beta);
    k_colsum<<<dim3(T_ / 256, 4, B_), 256, 0, stream>>>(x, s_buf, cx, cy);
    k_wt<<<dim3((COUT_ * CIN_ * K_) / 256), 256, 0, stream>>>(conv_w, cwT);
    k_conv<<<dim3(T_ / 64, COUT_ / 64, B_), 256, 0, stream>>>(
        x, s_buf, cwT, alpha, beta, cx, cy, out);
}

// Round 2
// 226.180 us; speedup vs baseline: 4.5350x; 4.5350x over previous
//
#include <hip/hip_runtime.h>
#include <hip/hip_bf16.h>
#include <stdint.h>

#define B_    16
#define CIN_  512
#define COUT_ 512
#define K_    3
#define T_    2048
#define S_    128
#define TP_   2064          // padded t rows: row = t+8, 8-row zero halo each side
#define CXP_  2050          // padded column-sum: idx = t+1, zero at both ends

#define LIN_SCALE  0.08838834764831845f   // 1/sqrt(128)
#define CONV_SCALE 0.014731391274719739f  // 1/sqrt(512*9)

typedef unsigned short u16;
typedef short s16x8 __attribute__((ext_vector_type(8)));
typedef float f32x4 __attribute__((ext_vector_type(4)));
typedef u16 u16x8 __attribute__((ext_vector_type(8)));

__device__ __forceinline__ u16 bf16r(float f) {
    uint32_t u = __float_as_uint(f);
    return (u16)((u + 0x7FFFu + ((u >> 16) & 1u)) >> 16);   // RNE
}

#define GLDS16(gsrc, ldst) \
    __builtin_amdgcn_global_load_lds((__attribute__((address_space(1))) void*)(gsrc), \
                                     (__attribute__((address_space(3))) void*)(ldst), 16, 0, 0)

// ---------------- K1: style projection  s[b,i]
__global__ void k_style(const float* __restrict__ c_trg,
                        const float* __restrict__ style_w,
                        const float* __restrict__ style_b,
                        float* __restrict__ s_out) {
    int idx = blockIdx.x * 256 + threadIdx.x;       // 0..8191
    int b = idx >> 9, i = idx & 511;
    const float4* c4 = reinterpret_cast<const float4*>(c_trg + b * S_);
    const float4* w4 = reinterpret_cast<const float4*>(style_w + (size_t)i * S_);
    float acc = 0.f;
#pragma unroll
    for (int j = 0; j < S_ / 4; ++j) {
        float4 a = c4[j], w = w4[j];
        acc += a.x * w.x + a.y * w.y + a.z * w.z + a.w * w.w;
    }
    s_out[idx] = acc * LIN_SCALE + style_b[i];
}

// ---------------- K2a: per-(o,i) tap sums:  W1 = sum_k (w+1), W2 = sum_k (w+1)^2
__global__ void k_wsum(const float* __restrict__ conv_w,
                       float* __restrict__ W1, float* __restrict__ W2) {
    int idx = blockIdx.x * 256 + threadIdx.x;   // o*512 + i
    const float* wr = conv_w + (size_t)idx * 3;
    float a0 = wr[0] + 1.f, a1 = wr[1] + 1.f, a2 = wr[2] + 1.f;
    W1[idx] = a0 + a1 + a2;
    W2[idx] = a0 * a0 + a1 * a1 + a2 * a2;
}

// ---------------- K2b: alpha/beta per (b,o) via GEMV on W1/W2. 1 wave per (b,o).
__global__ void k_stats2(const float* __restrict__ s,
                         const float* __restrict__ W1, const float* __restrict__ W2,
                         float* __restrict__ alpha, float* __restrict__ beta) {
    int bo = blockIdx.x;          // b*512 + o
    int b = bo >> 9, o = bo & 511;
    const float* sb = s + b * CIN_;
    const float* w1 = W1 + (size_t)o * CIN_;
    const float* w2 = W2 + (size_t)o * CIN_;
    int l = threadIdx.x;
    float sum = 0.f, sq = 0.f;
#pragma unroll
    for (int r = 0; r < 8; ++r) {
        float sv = sb[l + r * 64];
        sum += sv * w1[l + r * 64];
        sq  += sv * sv * w2[l + r * 64];
    }
#pragma unroll
    for (int off = 32; off; off >>= 1) { sum += __shfl_down(sum, off); sq += __shfl_down(sq, off); }
    if (l == 0) {
        float mean  = CONV_SCALE * sum * (1.0f / (CIN_ * K_));
        float demod = rsqrtf(CONV_SCALE * CONV_SCALE * sq + 1e-8f);
        alpha[bo] = demod * CONV_SCALE;
        beta[bo]  = demod * mean;
    }
}

// ---------------- K3: weight prepack into MFMA fragment-image order (bf16).
// wpk flat idx = ((((ob*16 + step)*3 + tap)*8 + grp)*64 + lane)*8 + j
// holds cw[o = ob*128+grp*16+(lane&15)][i = step*32+(lane>>4)*8+j][tap]
__global__ void k_prep_w(const float* __restrict__ conv_w, u16* __restrict__ wpk) {
    int idx = blockIdx.x * 256 + threadIdx.x;   // < 786432
    int j    = idx & 7;
    int lane = (idx >> 3) & 63;
    int grp  = (idx >> 9) & 7;
    int rest = idx >> 12;          // tap + 3*(step + 16*ob)
    int tap  = rest % 3;
    int so   = rest / 3;
    int step = so & 15, ob = so >> 4;
    int o = ob * 128 + grp * 16 + (lane & 15);
    int i = step * 32 + (lane >> 4) * 8 + j;
    wpk[idx] = bf16r(conv_w[((size_t)o * CIN_ + i) * 3 + tap]);
}

// ---------------- K4: y = s*x -> bf16, octet-interleaved + t-halo; fold in column sums.
// ybf[b][oct][tpad][8] : 16B chunk = y[b][oct*8..oct*8+7][t], tpad = t+8
__global__ void k_ytrans(const float* __restrict__ x, const float* __restrict__ s,
                         u16* __restrict__ ybf,
                         float* __restrict__ cxp, float* __restrict__ cyp) {
    int t = blockIdx.x * 256 + threadIdx.x;
    int oct = blockIdx.y, b = blockIdx.z;
    const float* xb = x + ((size_t)(b * CIN_ + oct * 8)) * T_ + t;
    const float* sb = s + b * CIN_ + oct * 8;
    float ax = 0.f, ay = 0.f;
    u16x8 pv;
#pragma unroll
    for (int j = 0; j < 8; ++j) {
        float xv = xb[(size_t)j * T_];
        float yv = sb[j] * xv;
        ax += xv; ay += yv;
        pv[j] = bf16r(yv);
    }
    *(u16x8*)(ybf + (((size_t)(b * 64 + oct)) * TP_ + t + 8) * 8) = pv;
    atomicAdd(&cxp[b * CXP_ + t + 1], ax);
    atomicAdd(&cyp[b * CXP_ + t + 1], ay);
    if (blockIdx.x == 0 && threadIdx.x < 8) {
        u16x8 z = {0, 0, 0, 0, 0, 0, 0, 0};
        *(u16x8*)(ybf + (((size_t)(b * 64 + oct)) * TP_ + threadIdx.x) * 8) = z;
    }
    if (blockIdx.x == 7 && threadIdx.x >= 248) {
        u16x8 z = {0, 0, 0, 0, 0, 0, 0, 0};
        *(u16x8*)(ybf + (((size_t)(b * 64 + oct)) * TP_ + 2056 + (threadIdx.x - 248)) * 8) = z;
    }
}

// ---------------- K5: MFMA conv. 128o x 128t tile, 4 waves x (64x64), BK=32, 3 taps.
__global__ __launch_bounds__(256) void k_conv(
    const u16* __restrict__ wpk, const u16* __restrict__ ybf,
    const float* __restrict__ alpha, const float* __restrict__ beta,
    const float* __restrict__ cxp, const float* __restrict__ cyp,
    float* __restrict__ out) {

    __shared__ __align__(16) char smem[33792];   // As: 24576 (3 tap x 8 grp x 1KB), Xs: 9216 (4 g x 144 x 16B)

    const int tid  = threadIdx.x;
    const int lane = tid & 63;
    const int w    = tid >> 6;
    const int wr   = w >> 1, wc = w & 1;
    const int t0   = blockIdx.x * 128;
    const int ob   = blockIdx.y;
    const int b    = blockIdx.z;

    f32x4 acc[4][4] = {};

    const char* wsrc  = (const char*)wpk + (size_t)(ob * 16) * 24576 + (w * 6) * 1024 + lane * 16;
    const char* ybase = (const char*)ybf + ((size_t)b * 64) * (TP_ * 16);

    const int as_lane = wr * 4096 + lane * 16;                              // + tap*8192 + m*1024
    const int xs_lane = 24576 + (lane >> 4) * 2304 + ((lane & 15) + 7) * 16 + wc * 1024;  // + tap*16 + n*256

    for (int step = 0; step < 16; ++step) {
        __syncthreads();
        // stage A: 24KB linear copy, 6 rounds/wave
#pragma unroll
        for (int r = 0; r < 6; ++r)
            GLDS16(wsrc + (size_t)step * 24576 + r * 1024, smem + (w * 6 + r) * 1024);
        // stage B: 9KB, rounds rb = w, w+4, (w==0 also 8)
#pragma unroll
        for (int rb = w; rb < 9; rb += 4) {
            int c  = rb * 64 + lane;
            int g  = c / 144;
            int rr = c - g * 144;
            GLDS16(ybase + ((size_t)((step * 4 + g) * TP_) + t0 + rr) * 16,
                   smem + 24576 + rb * 1024);
        }
        __syncthreads();

#pragma unroll
        for (int tap = 0; tap < 3; ++tap) {
            s16x8 af[4], bq[4];
#pragma unroll
            for (int m = 0; m < 4; ++m)
                af[m] = *(const s16x8*)(smem + tap * 8192 + as_lane + m * 1024);
#pragma unroll
            for (int n = 0; n < 4; ++n)
                bq[n] = *(const s16x8*)(smem + xs_lane + tap * 16 + n * 256);
#pragma unroll
            for (int m = 0; m < 4; ++m)
#pragma unroll
                for (int n = 0; n < 4; ++n)
                    acc[m][n] = __builtin_amdgcn_mfma_f32_16x16x32_bf16(af[m], bq[n], acc[m][n], 0, 0, 0);
        }
    }

    // epilogue: out = alpha*(G + cy3) - beta*cx3
    const int lr = lane >> 4, lc = lane & 15;
    const int o0 = ob * 128 + wr * 64;
    const int tw = t0 + wc * 64;
    const float* al  = alpha + b * COUT_ + o0;
    const float* be  = beta  + b * COUT_ + o0;
    const float* cxb = cxp + b * CXP_;
    const float* cyb = cyp + b * CXP_;
    float* op = out + ((size_t)(b * COUT_ + o0)) * T_;

#pragma unroll
    for (int n = 0; n < 4; ++n) {
        int t = tw + n * 16 + lc;
        float cx3 = cxb[t] + cxb[t + 1] + cxb[t + 2];
        float cy3 = cyb[t] + cyb[t + 1] + cyb[t + 2];
#pragma unroll
        for (int m = 0; m < 4; ++m)
#pragma unroll
            for (int q = 0; q < 4; ++q) {
                int o = m * 16 + lr * 4 + q;
                op[(size_t)o * T_ + t] = al[o] * (acc[m][n][q] + cy3) - be[o] * cx3;
            }
    }
}

extern "C" void kernel_launch(void* const* d_in, const int* in_sizes, int n_in,
                              void* d_out, int out_size, void* d_ws, size_t ws_size,
                              hipStream_t stream) {
    const float* x       = (const float*)d_in[0];
    const float* c_trg   = (const float*)d_in[1];
    const float* style_w = (const float*)d_in[2];
    const float* style_b = (const float*)d_in[3];
    const float* conv_w  = (const float*)d_in[4];
    float* out = (float*)d_out;
    float* ws  = (float*)d_ws;

    float* s_buf = ws;                      // 8192
    float* alpha = ws + 8192;               // 8192
    float* beta  = ws + 16384;              // 8192
    float* cxp   = ws + 24576;              // 32800
    float* cyp   = ws + 57376;              // 32800
    float* W1    = ws + 90176;              // 262144
    float* W2    = ws + 352320;             // 262144
    u16*   wpk   = (u16*)(ws + 614464);     // 786432 u16
    u16*   ybf   = (u16*)(ws + 1007680);    // 16*64*2064*8 u16 (~33.8 MB)

    hipMemsetAsync(cxp, 0, (size_t)2 * CXP_ * B_ * sizeof(float), stream);

    k_style <<<dim3((B_ * CIN_) / 256), 256, 0, stream>>>(c_trg, style_w, style_b, s_buf);
    k_wsum  <<<dim3((COUT_ * CIN_) / 256), 256, 0, stream>>>(conv_w, W1, W2);
    k_prep_w<<<dim3((COUT_ * CIN_ * K_) / 256), 256, 0, stream>>>(conv_w, wpk);
    k_stats2<<<dim3(B_ * COUT_), 64, 0, stream>>>(s_buf, W1, W2, alpha, beta);
    k_ytrans<<<dim3(T_ / 256, CIN_ / 8, B_), 256, 0, stream>>>(x, s_buf, ybf, cxp, cyp);
    k_conv  <<<dim3(T_ / 128, COUT_ / 128, B_), 256, 0, stream>>>(wpk, ybf, alpha, beta, cxp, cyp, out);
}

// Round 3
// 190.677 us; speedup vs baseline: 5.3794x; 1.1862x over previous
//
#include <hip/hip_runtime.h>
#include <hip/hip_bf16.h>
#include <stdint.h>

#define B_    16
#define CIN_  512
#define COUT_ 512
#define K_    3
#define T_    2048
#define S_    128
#define TP_   2064          // padded t rows: row = t+8, 8-row zero halo each side
#define CXP_  2050          // padded column-sum: idx = t+1, zero at both ends

#define LIN_SCALE  0.08838834764831845f   // 1/sqrt(128)
#define CONV_SCALE 0.014731391274719739f  // 1/sqrt(512*9)

typedef unsigned short u16;
typedef short s16x8 __attribute__((ext_vector_type(8)));
typedef float f32x4 __attribute__((ext_vector_type(4)));
typedef u16 u16x8 __attribute__((ext_vector_type(8)));

__device__ __forceinline__ u16 bf16r(float f) {
    uint32_t u = __float_as_uint(f);
    return (u16)((u + 0x7FFFu + ((u >> 16) & 1u)) >> 16);   // RNE
}

#define GLDS16(gsrc, ldst) \
    __builtin_amdgcn_global_load_lds((__attribute__((address_space(1))) void*)(gsrc), \
                                     (__attribute__((address_space(3))) void*)(ldst), 16, 0, 0)

// ---------------- K1: style projection  s[b,i]
__global__ void k_style(const float* __restrict__ c_trg,
                        const float* __restrict__ style_w,
                        const float* __restrict__ style_b,
                        float* __restrict__ s_out) {
    int idx = blockIdx.x * 256 + threadIdx.x;       // 0..8191
    int b = idx >> 9, i = idx & 511;
    const float4* c4 = reinterpret_cast<const float4*>(c_trg + b * S_);
    const float4* w4 = reinterpret_cast<const float4*>(style_w + (size_t)i * S_);
    float acc = 0.f;
#pragma unroll
    for (int j = 0; j < S_ / 4; ++j) {
        float4 a = c4[j], w = w4[j];
        acc += a.x * w.x + a.y * w.y + a.z * w.z + a.w * w.w;
    }
    s_out[idx] = acc * LIN_SCALE + style_b[i];
}

// ---------------- K2a: per-(o,i) tap sums:  W1 = sum_k (w+1), W2 = sum_k (w+1)^2
__global__ void k_wsum(const float* __restrict__ conv_w,
                       float* __restrict__ W1, float* __restrict__ W2) {
    int idx = blockIdx.x * 256 + threadIdx.x;   // o*512 + i
    const float* wr = conv_w + (size_t)idx * 3;
    float a0 = wr[0] + 1.f, a1 = wr[1] + 1.f, a2 = wr[2] + 1.f;
    W1[idx] = a0 + a1 + a2;
    W2[idx] = a0 * a0 + a1 * a1 + a2 * a2;
}

// ---------------- K2b: alpha/beta per (b,o) via GEMV on W1/W2. 1 wave per (b,o).
__global__ void k_stats2(const float* __restrict__ s,
                         const float* __restrict__ W1, const float* __restrict__ W2,
                         float* __restrict__ alpha, float* __restrict__ beta) {
    int bo = blockIdx.x;          // b*512 + o
    int b = bo >> 9, o = bo & 511;
    const float* sb = s + b * CIN_;
    const float* w1 = W1 + (size_t)o * CIN_;
    const float* w2 = W2 + (size_t)o * CIN_;
    int l = threadIdx.x;
    float sum = 0.f, sq = 0.f;
#pragma unroll
    for (int r = 0; r < 8; ++r) {
        float sv = sb[l + r * 64];
        sum += sv * w1[l + r * 64];
        sq  += sv * sv * w2[l + r * 64];
    }
#pragma unroll
    for (int off = 32; off; off >>= 1) { sum += __shfl_down(sum, off); sq += __shfl_down(sq, off); }
    if (l == 0) {
        float mean  = CONV_SCALE * sum * (1.0f / (CIN_ * K_));
        float demod = rsqrtf(CONV_SCALE * CONV_SCALE * sq + 1e-8f);
        alpha[bo] = demod * CONV_SCALE;
        beta[bo]  = demod * mean;
    }
}

// ---------------- K3: weight prepack into MFMA fragment-image order (bf16).
// wpk flat idx = ((((ob*16 + step)*3 + tap)*8 + grp)*64 + lane)*8 + j
// holds cw[o = ob*128+grp*16+(lane&15)][i = step*32+(lane>>4)*8+j][tap]
__global__ void k_prep_w(const float* __restrict__ conv_w, u16* __restrict__ wpk) {
    int idx = blockIdx.x * 256 + threadIdx.x;   // < 786432
    int j    = idx & 7;
    int lane = (idx >> 3) & 63;
    int grp  = (idx >> 9) & 7;
    int rest = idx >> 12;          // tap + 3*(step + 16*ob)
    int tap  = rest % 3;
    int so   = rest / 3;
    int step = so & 15, ob = so >> 4;
    int o = ob * 128 + grp * 16 + (lane & 15);
    int i = step * 32 + (lane >> 4) * 8 + j;
    wpk[idx] = bf16r(conv_w[((size_t)o * CIN_ + i) * 3 + tap]);
}

// ---------------- K4: y = s*x -> bf16, octet-interleaved + t-halo; per-octet partial col sums.
// ybf[b][oct][tpad][8] : 16B chunk = y[b][oct*8..oct*8+7][t], tpad = t+8
// partials: cxpart/cypart [b*64+oct][t]  (stored in d_out scratch, no atomics)
__global__ void k_ytrans(const float* __restrict__ x, const float* __restrict__ s,
                         u16* __restrict__ ybf,
                         float* __restrict__ cxpart, float* __restrict__ cypart) {
    int t = blockIdx.x * 256 + threadIdx.x;
    int oct = blockIdx.y, b = blockIdx.z;
    const float* xb = x + ((size_t)(b * CIN_ + oct * 8)) * T_ + t;
    const float* sb = s + b * CIN_ + oct * 8;
    float ax = 0.f, ay = 0.f;
    u16x8 pv;
#pragma unroll
    for (int j = 0; j < 8; ++j) {
        float xv = xb[(size_t)j * T_];
        float yv = sb[j] * xv;
        ax += xv; ay += yv;
        pv[j] = bf16r(yv);
    }
    *(u16x8*)(ybf + (((size_t)(b * 64 + oct)) * TP_ + t + 8) * 8) = pv;
    cxpart[((size_t)(b * 64 + oct)) * T_ + t] = ax;
    cypart[((size_t)(b * 64 + oct)) * T_ + t] = ay;
    if (blockIdx.x == 0 && threadIdx.x < 8) {
        u16x8 z = {0, 0, 0, 0, 0, 0, 0, 0};
        *(u16x8*)(ybf + (((size_t)(b * 64 + oct)) * TP_ + threadIdx.x) * 8) = z;
    }
    if (blockIdx.x == 7 && threadIdx.x >= 248) {
        u16x8 z = {0, 0, 0, 0, 0, 0, 0, 0};
        *(u16x8*)(ybf + (((size_t)(b * 64 + oct)) * TP_ + 2056 + (threadIdx.x - 248)) * 8) = z;
    }
}

// ---------------- K4b: reduce 64 octet partials -> padded column sums
__global__ void k_colred(const float* __restrict__ cxpart, const float* __restrict__ cypart,
                         float* __restrict__ cxp, float* __restrict__ cyp) {
    int t = blockIdx.x * 256 + threadIdx.x;
    int b = blockIdx.y;
    float sx = 0.f, sy = 0.f;
#pragma unroll 8
    for (int oct = 0; oct < 64; ++oct) {
        sx += cxpart[((size_t)(b * 64 + oct)) * T_ + t];
        sy += cypart[((size_t)(b * 64 + oct)) * T_ + t];
    }
    cxp[b * CXP_ + t + 1] = sx;
    cyp[b * CXP_ + t + 1] = sy;
    if (t == 0)        { cxp[b * CXP_] = 0.f;        cyp[b * CXP_] = 0.f; }
    if (t == T_ - 1)   { cxp[b * CXP_ + T_ + 1] = 0.f; cyp[b * CXP_ + T_ + 1] = 0.f; }
}

// ---------------- K5: MFMA conv, 2-phase double-buffered pipeline.
// 128o x 128t tile, 4 waves x (64x64), BK=32, 3 taps. XCD-aware block swizzle.
__global__ __launch_bounds__(256) void k_conv(
    const u16* __restrict__ wpk, const u16* __restrict__ ybf,
    const float* __restrict__ alpha, const float* __restrict__ beta,
    const float* __restrict__ cxp, const float* __restrict__ cyp,
    float* __restrict__ out) {

    __shared__ __align__(16) char smem[2 * 33792];   // per buf: As 24576 (3tap x 8grp x 1KB), Xs 9216

    const int tid  = threadIdx.x;
    const int lane = tid & 63;
    const int w    = tid >> 6;
    const int wr   = w >> 1, wc = w & 1;

    // XCD swizzle: 1024 blocks, 8 XCDs, 128 contiguous wgs per XCD -> 2 batches/XCD L2
    const int bid = blockIdx.x;
    const int wg  = (bid & 7) * 128 + (bid >> 3);
    const int b   = wg >> 6;
    const int ob  = (wg >> 4) & 3;
    const int t0  = (wg & 15) * 128;

    f32x4 acc[4][4] = {};

    const char* wsrc  = (const char*)wpk + (size_t)(ob * 16) * 24576 + (w * 6) * 1024 + lane * 16;
    const char* ybase = (const char*)ybf + ((size_t)b * 64) * (TP_ * 16);

    const int as_lane = wr * 4096 + lane * 16;                              // + tap*8192 + m*1024
    const int xs_lane = 24576 + (lane >> 4) * 2304 + ((lane & 15) + 7) * 16 + wc * 1024;  // + tap*16 + n*256

#define STAGE(buf, step)                                                              \
    do {                                                                              \
        char* dst = smem + (buf) * 33792;                                             \
        _Pragma("unroll")                                                             \
        for (int r = 0; r < 6; ++r)                                                   \
            GLDS16(wsrc + (size_t)(step) * 24576 + r * 1024, dst + (w * 6 + r) * 1024); \
        _Pragma("unroll")                                                             \
        for (int rb = w; rb < 9; rb += 4) {                                           \
            int c  = rb * 64 + lane;                                                  \
            int g  = c / 144;                                                         \
            int rr = c - g * 144;                                                     \
            GLDS16(ybase + ((size_t)(((step) * 4 + g) * TP_) + t0 + rr) * 16,         \
                   dst + 24576 + rb * 1024);                                          \
        }                                                                             \
    } while (0)

    STAGE(0, 0);
    __syncthreads();

    int cur = 0;
    for (int step = 0; step < 16; ++step) {
        if (step < 15) STAGE(cur ^ 1, step + 1);      // prefetch next tile (in flight during MFMA)

        const char* base = smem + cur * 33792;
#pragma unroll
        for (int tap = 0; tap < 3; ++tap) {
            s16x8 af[4], bq[4];
#pragma unroll
            for (int m = 0; m < 4; ++m)
                af[m] = *(const s16x8*)(base + tap * 8192 + as_lane + m * 1024);
#pragma unroll
            for (int n = 0; n < 4; ++n)
                bq[n] = *(const s16x8*)(base + xs_lane + tap * 16 + n * 256);
#pragma unroll
            for (int m = 0; m < 4; ++m)
#pragma unroll
                for (int n = 0; n < 4; ++n)
                    acc[m][n] = __builtin_amdgcn_mfma_f32_16x16x32_bf16(af[m], bq[n], acc[m][n], 0, 0, 0);
        }
        __syncthreads();   // implicit vmcnt(0)+lgkmcnt(0): prefetch landed, all waves done reading
        cur ^= 1;
    }
#undef STAGE

    // epilogue: out = alpha*(G + cy3) - beta*cx3
    const int lr = lane >> 4, lc = lane & 15;
    const int o0 = ob * 128 + wr * 64;
    const int tw = t0 + wc * 64;
    const float* al  = alpha + b * COUT_ + o0;
    const float* be  = beta  + b * COUT_ + o0;
    const float* cxb = cxp + b * CXP_;
    const float* cyb = cyp + b * CXP_;
    float* op = out + ((size_t)(b * COUT_ + o0)) * T_;

#pragma unroll
    for (int n = 0; n < 4; ++n) {
        int t = tw + n * 16 + lc;
        float cx3 = cxb[t] + cxb[t + 1] + cxb[t + 2];
        float cy3 = cyb[t] + cyb[t + 1] + cyb[t + 2];
#pragma unroll
        for (int m = 0; m < 4; ++m)
#pragma unroll
            for (int q = 0; q < 4; ++q) {
                int o = m * 16 + lr * 4 + q;
                op[(size_t)o * T_ + t] = al[o] * (acc[m][n][q] + cy3) - be[o] * cx3;
            }
    }
}

extern "C" void kernel_launch(void* const* d_in, const int* in_sizes, int n_in,
                              void* d_out, int out_size, void* d_ws, size_t ws_size,
                              hipStream_t stream) {
    const float* x       = (const float*)d_in[0];
    const float* c_trg   = (const float*)d_in[1];
    const float* style_w = (const float*)d_in[2];
    const float* style_b = (const float*)d_in[3];
    const float* conv_w  = (const float*)d_in[4];
    float* out = (float*)d_out;
    float* ws  = (float*)d_ws;

    float* s_buf = ws;                      // 8192
    float* alpha = ws + 8192;               // 8192
    float* beta  = ws + 16384;              // 8192
    float* cxp   = ws + 24576;              // 32800
    float* cyp   = ws + 57376;              // 32800
    float* W1    = ws + 90176;              // 262144
    float* W2    = ws + 352320;             // 262144
    u16*   wpk   = (u16*)(ws + 614464);     // 786432 u16
    u16*   ybf   = (u16*)(ws + 1007680);    // 16*64*2064*8 u16 (~33.8 MB)

    // out is used as scratch for the column-sum partials (fully overwritten by k_conv)
    float* cxpart = out;                    // 16*64*2048 = 2.1M floats
    float* cypart = out + (size_t)B_ * 64 * T_;

    k_style <<<dim3((B_ * CIN_) / 256), 256, 0, stream>>>(c_trg, style_w, style_b, s_buf);
    k_wsum  <<<dim3((COUT_ * CIN_) / 256), 256, 0, stream>>>(conv_w, W1, W2);
    k_prep_w<<<dim3((COUT_ * CIN_ * K_) / 256), 256, 0, stream>>>(conv_w, wpk);
    k_stats2<<<dim3(B_ * COUT_), 64, 0, stream>>>(s_buf, W1, W2, alpha, beta);
    k_ytrans<<<dim3(T_ / 256, CIN_ / 8, B_), 256, 0, stream>>>(x, s_buf, ybf, cxpart, cypart);
    k_colred<<<dim3(T_ / 256, B_), 256, 0, stream>>>(cxpart, cypart, cxp, cyp);
    k_conv  <<<dim3(1024), 256, 0, stream>>>(wpk, ybf, alpha, beta, cxp, cyp, out);
}